// Round 8
// baseline (71.950 us; speedup 1.0000x reference)
//
#include <hip/hip_runtime.h>
#include <hip/hip_bf16.h>

constexpr int HID = 1024;
constexpr int KD  = 16;    // probe directions
constexpr int NT  = 512;   // threads per block (8 waves)
constexpr int NW  = 8;     // waves per block
constexpr int TM  = 16;    // rows per tile

typedef short bf16x8 __attribute__((ext_vector_type(8)));   // MFMA A/B frag
typedef float f32x4  __attribute__((ext_vector_type(4)));   // MFMA C/D frag

__device__ __forceinline__ short f2b(float x) {
    __hip_bfloat16 b = __float2bfloat16(x);
    return *reinterpret_cast<short*>(&b);
}

// Round-7 diagnosis: latency-bound at 21% occupancy (2 blocks/CU, 5 barriers/
// tile, LDS 78.8KB). Fix: drop the 32KB Ht LDS tile -- the MFMA A-fragment
// pattern (lane(r,q) reads 32B at H[r][kt*32+q*8]) already covers each 128B
// line exactly once per wave, so load it STRAIGHT from global; epilogue
// re-reads h from global too (L2/L3-hot, exact f32). LDS 46KB -> 3 blocks/CU,
// 4 barriers/tile, grid 1024 to fill residency.
__global__ __launch_bounds__(NT)
void probe_removal_mfma5(const float* __restrict__ H,
                         const float* __restrict__ Qf,
                         float* __restrict__ out,
                         int ntiles)
{
    const int t    = threadIdx.x;
    const int lane = t & 63;
    const int w    = t >> 6;       // wave: owns hidden-slice [w*128, w*128+128)
    const int r    = lane & 15;
    const int q    = lane >> 4;

    __shared__ __align__(16) float red[NW][TM][20];          // coef partials [wave][row][dir]
    __shared__ float s2red[NW][TM];                          // ||h||^2 partials
    __shared__ __align__(16) float outl[TM][NW*68 + 4];      // 35 KB out staging (row stride 548)

    // ---------- coef GEMM B-frag (the ONLY persistent fragment, 16 VGPRs) ----------
    // B[k][n=dir=r], k = w*128+kt*32+q*8+i
    bf16x8 bq[4];
    #pragma unroll
    for (int kt = 0; kt < 4; ++kt)
        #pragma unroll
        for (int i = 0; i < 8; ++i)
            bq[kt][i] = f2b(Qf[(w*128 + kt*32 + q*8 + i)*KD + r]);

    for (int tile = blockIdx.x; tile < ntiles; tile += gridDim.x) {
        const float* Hbase = H + (size_t)tile*TM*HID;
        const float* hrow  = Hbase + r*HID + w*128;   // this lane's row slice

        // launder Qf per tile so the per-use epilogue Q loads are NOT
        // hoisted by LICM into persistent registers (round-5/6 spill mode)
        const float* Qv = Qf;
        asm volatile("" : "+s"(Qv));

        // ---- C: A-frags DIRECT from global (full-line coverage), s2 in f32 ----
        bf16x8 af[4];
        float s2 = 0.f;
        #pragma unroll
        for (int kt = 0; kt < 4; ++kt) {
            const float4 x = *reinterpret_cast<const float4*>(hrow + kt*32 + q*8);
            const float4 y = *reinterpret_cast<const float4*>(hrow + kt*32 + q*8 + 4);
            s2 = fmaf(x.x,x.x, fmaf(x.y,x.y, fmaf(x.z,x.z, fmaf(x.w,x.w, s2))));
            s2 = fmaf(y.x,y.x, fmaf(y.y,y.y, fmaf(y.z,y.z, fmaf(y.w,y.w, s2))));
            af[kt][0]=f2b(x.x); af[kt][1]=f2b(x.y); af[kt][2]=f2b(x.z); af[kt][3]=f2b(x.w);
            af[kt][4]=f2b(y.x); af[kt][5]=f2b(y.y); af[kt][6]=f2b(y.z); af[kt][7]=f2b(y.w);
        }
        f32x4 acc = {0.f, 0.f, 0.f, 0.f};
        #pragma unroll
        for (int kt = 0; kt < 4; ++kt)
            acc = __builtin_amdgcn_mfma_f32_16x16x32_bf16(af[kt], bq[kt], acc, 0, 0, 0);

        s2 += __shfl_xor(s2, 16);
        s2 += __shfl_xor(s2, 32);

        #pragma unroll
        for (int i = 0; i < 4; ++i) red[w][q*4 + i][r] = acc[i];   // C[m=q*4+i][n=dir=r]
        if (q == 0) s2red[w][r] = s2;
        __syncthreads();   // b1: red ready

        // ---- R: cross-wave reduce -> coefs, scale, pb frag ----
        float cf[8] = {0,0,0,0,0,0,0,0};
        if (q < 2) {
            #pragma unroll
            for (int w2 = 0; w2 < NW; ++w2) {
                const float4 a  = *reinterpret_cast<const float4*>(&red[w2][r][q*8]);
                const float4 bb = *reinterpret_cast<const float4*>(&red[w2][r][q*8 + 4]);
                cf[0]+=a.x;  cf[1]+=a.y;  cf[2]+=a.z;  cf[3]+=a.w;
                cf[4]+=bb.x; cf[5]+=bb.y; cf[6]+=bb.z; cf[7]+=bb.w;
            }
        }
        float s2tot = 0.f;
        #pragma unroll
        for (int w2 = 0; w2 < NW; ++w2) s2tot += s2red[w2][r];   // broadcast reads

        float sc2 = 0.f;
        #pragma unroll
        for (int i = 0; i < 8; ++i) sc2 = fmaf(cf[i], cf[i], sc2);
        sc2 += __shfl_xor(sc2, 16);
        sc2 += __shfl_xor(sc2, 32);
        const float scale = rsqrtf(fmaxf(1.0f - sc2 / s2tot, 1e-20f));

        bf16x8 pb;   // B[k=dir][n=row=r]; q>=2 lanes hold K-pad zeros
        #pragma unroll
        for (int i = 0; i < 8; ++i) pb[i] = f2b(cf[i]);

        // ---- E+S: two half passes (epilogue MFMA -> outl -> coalesced store) ----
        const f32x4 zero4 = {0.f, 0.f, 0.f, 0.f};
        #pragma unroll
        for (int pass = 0; pass < 2; ++pass) {
            #pragma unroll
            for (int jj = 0; jj < 4; ++jj) {
                const int j = pass*4 + jj;
                // epilogue A-frag per-use from L2-hot Qf: A[m=col=r][k=dir pad32]
                bf16x8 aqj;
                if (q < 2) {
                    const float* src = Qv + (w*128 + j*16 + r)*KD + q*8;
                    const float4 x = *reinterpret_cast<const float4*>(src);
                    const float4 y = *reinterpret_cast<const float4*>(src + 4);
                    aqj[0]=f2b(x.x); aqj[1]=f2b(x.y); aqj[2]=f2b(x.z); aqj[3]=f2b(x.w);
                    aqj[4]=f2b(y.x); aqj[5]=f2b(y.y); aqj[6]=f2b(y.z); aqj[7]=f2b(y.w);
                } else {
                    #pragma unroll
                    for (int i = 0; i < 8; ++i) aqj[i] = 0;
                }
                f32x4 d = __builtin_amdgcn_mfma_f32_16x16x32_bf16(aqj, pb, zero4, 0, 0, 0);
                // h re-read straight from global (L2/L3-hot, exact f32);
                // lane holds out rows-of-D: row r, cols w*128 + j*16 + q*4 + {0..3}
                const float4 hx = *reinterpret_cast<const float4*>(hrow + j*16 + q*4);
                f32x4 o;
                o[0] = (hx.x - d[0]) * scale;
                o[1] = (hx.y - d[1]) * scale;
                o[2] = (hx.z - d[2]) * scale;
                o[3] = (hx.w - d[3]) * scale;
                *reinterpret_cast<f32x4*>(&outl[r][w*68 + jj*16 + q*4]) = o;
            }
            __syncthreads();   // outl ready

            // coalesced store of this half: full 128B lines only
            #pragma unroll
            for (int p = 0; p < 4; ++p) {
                const int flat = t + p*NT;           // float4 idx in half-tile
                const int rr  = flat >> 7;
                const int idx = flat & 127;
                const int ww  = idx >> 4, i4 = idx & 15;
                const float4 v = *reinterpret_cast<const float4*>(&outl[rr][ww*68 + i4*4]);
                const f32x4 vv = {v.x, v.y, v.z, v.w};
                float* dst = out + ((size_t)tile*TM + rr)*HID + ww*128 + pass*64 + i4*4;
                __builtin_nontemporal_store(vv, reinterpret_cast<f32x4*>(dst));
            }
            if (pass == 0) __syncthreads();   // outl free for pass 1
            // (post-pass-1 barrier elided: next tile's b1 orders outl reuse)
        }
    }
}

extern "C" void kernel_launch(void* const* d_in, const int* in_sizes, int n_in,
                              void* d_out, int out_size, void* d_ws, size_t ws_size,
                              hipStream_t stream) {
    const float* H  = (const float*)d_in[0];   // [8,4096,1024] f32
    const float* Qf = (const float*)d_in[1];   // [1024,16] f32, orthonormal cols
    float* outp     = (float*)d_out;
    const int nrows  = in_sizes[0] / HID;      // 32768
    const int ntiles = nrows / TM;             // 2048

    // LDS ~46KB -> 3 blocks/CU resident capacity = 768; grid 1024 = 2 tiles/block
    dim3 grid(1024), block(NT);
    hipLaunchKernelGGL(probe_removal_mfma5, grid, block, 0, stream,
                       H, Qf, outp, ntiles);
}